// Round 2
// baseline (797.461 us; speedup 1.0000x reference)
//
#include <hip/hip_runtime.h>
#include <math.h>

typedef __bf16 bf16;
typedef bf16 bf16x8 __attribute__((ext_vector_type(8)));
typedef float f32x4 __attribute__((ext_vector_type(4)));

#define EPS_F16 0.0009765625f   // jnp.finfo(float16).eps

// B=8, N=2048, C=2048, H=16, D=128, M=B*N=16384, K=C=2048

// ---------------- fp32 -> bf16 cast, 8 elems/thread ----------------
__global__ __launch_bounds__(256) void k_cast8(const float* __restrict__ in,
                                               bf16* __restrict__ out,
                                               long long n8) {
  long long i = (long long)blockIdx.x * blockDim.x + threadIdx.x;
  if (i >= n8) return;
  const float4* in4 = (const float4*)in;
  float4 a = in4[i * 2];
  float4 b = in4[i * 2 + 1];
  bf16x8 o;
  o[0] = (bf16)a.x; o[1] = (bf16)a.y; o[2] = (bf16)a.z; o[3] = (bf16)a.w;
  o[4] = (bf16)b.x; o[5] = (bf16)b.y; o[6] = (bf16)b.z; o[7] = (bf16)b.w;
  *(bf16x8*)(out + i * 8) = o;
}

// fp32 -> (hi, lo) bf16 split: hi = bf16(v), lo = bf16(v - hi)
__global__ __launch_bounds__(256) void k_cast_split(const float* __restrict__ in,
                                                    bf16* __restrict__ hi,
                                                    bf16* __restrict__ lo,
                                                    long long n8) {
  long long i = (long long)blockIdx.x * blockDim.x + threadIdx.x;
  if (i >= n8) return;
  const float4* in4 = (const float4*)in;
  float4 a = in4[i * 2];
  float4 b = in4[i * 2 + 1];
  float v[8] = {a.x, a.y, a.z, a.w, b.x, b.y, b.z, b.w};
  bf16x8 h, l;
#pragma unroll
  for (int j = 0; j < 8; ++j) {
    bf16 hh = (bf16)v[j];
    h[j] = hh;
    l[j] = (bf16)(v[j] - (float)hh);
  }
  *(bf16x8*)(hi + i * 8) = h;
  *(bf16x8*)(lo + i * 8) = l;
}

// ---------------- async global->LDS helper ----------------
__device__ __forceinline__ void gl2lds16(const void* g, void* l) {
  __builtin_amdgcn_global_load_lds(
      (const __attribute__((address_space(1))) void*)g,
      (__attribute__((address_space(3))) void*)l, 16, 0, 0);
}

// ---------------- GEMM (plain bf16): C = A (MxK) * Bm (NxK)^T ----------
// MODE 0: Cout row-major (M x 2048)
__global__ __launch_bounds__(256) void gemm_bt(const bf16* __restrict__ A,
                                               const bf16* __restrict__ Bm,
                                               float* __restrict__ Cout) {
  constexpr int K = 2048;
  __shared__ alignas(16) bf16 As[128 * 64];
  __shared__ alignas(16) bf16 Bs[128 * 64];
  const int tid  = threadIdx.x;
  const int lane = tid & 63;
  const int wave = tid >> 6;
  const int wr = (wave >> 1) * 64;
  const int wc = (wave & 1) * 64;
  const size_t bm = (size_t)blockIdx.y * 128;
  const size_t bn = (size_t)blockIdx.x * 128;

  const int r0 = tid >> 3;
  const int c0 = (tid & 7) * 8;
  const bf16* Ag = A + (bm + (size_t)r0) * K + c0;
  const bf16* Bg = Bm + (bn + (size_t)r0) * K + c0;

  f32x4 acc[4][4] = {};
  const int row = lane & 15;
  const int kg  = (lane >> 4) * 8;

  for (int k0 = 0; k0 < K; k0 += 64) {
#pragma unroll
    for (int p = 0; p < 4; ++p) {
      gl2lds16(Ag + (size_t)p * 32 * K + k0, &As[p * 2048 + tid * 8]);
      gl2lds16(Bg + (size_t)p * 32 * K + k0, &Bs[p * 2048 + tid * 8]);
    }
    __syncthreads();
#pragma unroll
    for (int kk = 0; kk < 64; kk += 32) {
      bf16x8 af[4], bfr[4];
#pragma unroll
      for (int i = 0; i < 4; ++i)
        af[i] = *(const bf16x8*)&As[(wr + i * 16 + row) * 64 + kk + kg];
#pragma unroll
      for (int j = 0; j < 4; ++j)
        bfr[j] = *(const bf16x8*)&Bs[(wc + j * 16 + row) * 64 + kk + kg];
#pragma unroll
      for (int i = 0; i < 4; ++i)
#pragma unroll
        for (int j = 0; j < 4; ++j)
          acc[i][j] = __builtin_amdgcn_mfma_f32_16x16x32_bf16(af[i], bfr[j],
                                                              acc[i][j], 0, 0, 0);
    }
    __syncthreads();
  }

  const int col = lane & 15;
  const int rb  = (lane >> 4) * 4;
#pragma unroll
  for (int i = 0; i < 4; ++i)
#pragma unroll
    for (int j = 0; j < 4; ++j)
#pragma unroll
      for (int r = 0; r < 4; ++r) {
        size_t gr = bm + wr + i * 16 + rb + r;
        size_t gc = bn + wc + j * 16 + col;
        Cout[gr * 2048 + gc] = acc[i][j][r];
      }
}

// ---------------- GEMM split-precision: w = (Ah+Al)(Bh+Bl)^T, 3-term ----------
// Output in (B,H,N,D) layout.
__global__ __launch_bounds__(256) void gemm_split(const bf16* __restrict__ Ah,
                                                  const bf16* __restrict__ Al,
                                                  const bf16* __restrict__ Bh,
                                                  const bf16* __restrict__ Bl,
                                                  float* __restrict__ Cout) {
  constexpr int K = 2048;
  __shared__ alignas(16) bf16 Ash[128 * 64];
  __shared__ alignas(16) bf16 Asl[128 * 64];
  __shared__ alignas(16) bf16 Bsh[128 * 64];
  __shared__ alignas(16) bf16 Bsl[128 * 64];
  const int tid  = threadIdx.x;
  const int lane = tid & 63;
  const int wave = tid >> 6;
  const int wr = (wave >> 1) * 64;
  const int wc = (wave & 1) * 64;
  const size_t bm = (size_t)blockIdx.y * 128;
  const size_t bn = (size_t)blockIdx.x * 128;

  const int r0 = tid >> 3;
  const int c0 = (tid & 7) * 8;
  const size_t aoff = (bm + (size_t)r0) * K + c0;
  const size_t boff = (bn + (size_t)r0) * K + c0;

  f32x4 acc[4][4] = {};
  const int row = lane & 15;
  const int kg  = (lane >> 4) * 8;

  for (int k0 = 0; k0 < K; k0 += 64) {
#pragma unroll
    for (int p = 0; p < 4; ++p) {
      size_t go = (size_t)p * 32 * K + k0;
      int lo = p * 2048 + tid * 8;
      gl2lds16(Ah + aoff + go, &Ash[lo]);
      gl2lds16(Al + aoff + go, &Asl[lo]);
      gl2lds16(Bh + boff + go, &Bsh[lo]);
      gl2lds16(Bl + boff + go, &Bsl[lo]);
    }
    __syncthreads();
#pragma unroll
    for (int kk = 0; kk < 64; kk += 32) {
      bf16x8 afh[4], afl[4], bfh[4], bfl[4];
#pragma unroll
      for (int i = 0; i < 4; ++i) {
        int o = (wr + i * 16 + row) * 64 + kk + kg;
        afh[i] = *(const bf16x8*)&Ash[o];
        afl[i] = *(const bf16x8*)&Asl[o];
      }
#pragma unroll
      for (int j = 0; j < 4; ++j) {
        int o = (wc + j * 16 + row) * 64 + kk + kg;
        bfh[j] = *(const bf16x8*)&Bsh[o];
        bfl[j] = *(const bf16x8*)&Bsl[o];
      }
#pragma unroll
      for (int i = 0; i < 4; ++i)
#pragma unroll
        for (int j = 0; j < 4; ++j) {
          acc[i][j] = __builtin_amdgcn_mfma_f32_16x16x32_bf16(afh[i], bfh[j],
                                                              acc[i][j], 0, 0, 0);
          acc[i][j] = __builtin_amdgcn_mfma_f32_16x16x32_bf16(afh[i], bfl[j],
                                                              acc[i][j], 0, 0, 0);
          acc[i][j] = __builtin_amdgcn_mfma_f32_16x16x32_bf16(afl[i], bfh[j],
                                                              acc[i][j], 0, 0, 0);
        }
    }
    __syncthreads();
  }

  const int col = lane & 15;
  const int rb  = (lane >> 4) * 4;
#pragma unroll
  for (int i = 0; i < 4; ++i)
#pragma unroll
    for (int j = 0; j < 4; ++j)
#pragma unroll
      for (int r = 0; r < 4; ++r) {
        size_t gr = bm + wr + i * 16 + rb + r;   // row in (B*N)
        size_t gc = bn + wc + j * 16 + col;      // out channel o = h*128+d
        // (b,h,n,d) = (gr>>11, gc>>7, gr&2047, gc&127)
        Cout[(((gr >> 11) * 16 + (gc >> 7)) * 2048 + (gr & 2047)) * 128 +
             (gc & 127)] = acc[i][j][r];
      }
}

// ---------------- scan pass A: chunk partial sums of w^2 ----------------
__global__ __launch_bounds__(128) void k_partial_wsq(const float* __restrict__ w,
                                                     float* __restrict__ psum) {
  int blk = blockIdx.x;  // bh*16 + chunk
  int d = threadIdx.x;
  const float* base =
      w + ((size_t)(blk >> 4) * 2048 + (size_t)(blk & 15) * 128) * 128 + d;
  float s = 0.f;
#pragma unroll 4
  for (int i = 0; i < 128; ++i) {
    float v = base[(size_t)i * 128];
    s += v * v;
  }
  psum[(size_t)blk * 128 + d] = s;
}

__global__ __launch_bounds__(256) void k_prefix(float* __restrict__ psum) {
  int idx = blockIdx.x * 256 + threadIdx.x;  // bh*128 + d
  int bh = idx >> 7, d = idx & 127;
  float run = 0.f;
#pragma unroll
  for (int c = 0; c < 16; ++c) {
    size_t o = ((size_t)bh * 16 + c) * 128 + d;
    float v = psum[o];
    psum[o] = run;
    run += v;
  }
}

__device__ __forceinline__ int swz(int i, int j) { return i * 128 + (j ^ (i & 31)); }

__global__ __launch_bounds__(128) void k_tmp(const float* __restrict__ w,
                                             const float* __restrict__ pre,
                                             const float* __restrict__ dbias,
                                             const float* __restrict__ temp,
                                             float* __restrict__ tmp) {
  __shared__ float ratio[128 * 128];
  int blk = blockIdx.x;
  int bh = blk >> 4, chunk = blk & 15;
  int h = bh & 15;
  int d = threadIdx.x;
  const float* base =
      w + ((size_t)bh * 2048 + (size_t)chunk * 128) * 128 + d;
  float cum = pre[((size_t)bh * 16 + chunk) * 128 + d];
  for (int i = 0; i < 128; ++i) {
    float v = base[(size_t)i * 128];
    float sq = v * v;
    cum += sq;
    float dn = fmaxf(cum, EPS_F16);
    ratio[swz(i, d)] = sq / dn;
  }
  __syncthreads();
  float s = 0.f;
#pragma unroll 8
  for (int j = 0; j < 128; ++j) s += ratio[swz(d, j)];
  int n = chunk * 128 + d;
  tmp[(size_t)bh * 2048 + n] = (s + 128.f * dbias[h * 2048 + n]) * temp[h];
}

__global__ __launch_bounds__(256) void k_softmax(const float* __restrict__ tmp,
                                                 float* __restrict__ Pi) {
  int idx = blockIdx.x * 256 + threadIdx.x;  // b*2048 + n
  int b = idx >> 11, n = idx & 2047;
  float v[16];
  float mx = -1e30f;
#pragma unroll
  for (int h = 0; h < 16; ++h) {
    v[h] = tmp[((size_t)(b * 16 + h)) * 2048 + n];
    mx = fmaxf(mx, v[h]);
  }
  float s = 0.f;
#pragma unroll
  for (int h = 0; h < 16; ++h) {
    v[h] = expf(v[h] - mx);
    s += v[h];
  }
  float inv = 1.f / s;
#pragma unroll
  for (int h = 0; h < 16; ++h)
    Pi[((size_t)(b * 16 + h)) * 2048 + n] = v[h] * inv;
}

__global__ __launch_bounds__(128) void k_partial2(const float* __restrict__ w,
                                                  const float* __restrict__ Pi,
                                                  float* __restrict__ psum,
                                                  float* __restrict__ pisum) {
  int blk = blockIdx.x;
  int bh = blk >> 4, chunk = blk & 15;
  int d = threadIdx.x;
  const float* base =
      w + ((size_t)bh * 2048 + (size_t)chunk * 128) * 128 + d;
  const float* pib = Pi + (size_t)bh * 2048 + (size_t)chunk * 128;
  float s = 0.f, sp = 0.f;
#pragma unroll 4
  for (int i = 0; i < 128; ++i) {
    float p = pib[i];
    float v = base[(size_t)i * 128];
    s += v * v * p;
    sp += p;
  }
  psum[(size_t)blk * 128 + d] = s;
  if (d == 0) pisum[blk] = sp;
}

__global__ __launch_bounds__(128) void k_prefix_pi(float* __restrict__ pisum) {
  int bh = threadIdx.x;  // 128 = B*H
  float run = 0.f;
#pragma unroll
  for (int c = 0; c < 16; ++c) {
    int o = bh * 16 + c;
    float v = pisum[o];
    pisum[o] = run;
    run += v;
  }
}

__global__ __launch_bounds__(128) void k_y(const float* __restrict__ w,
                                           const float* __restrict__ Pi,
                                           const float* __restrict__ pre2,
                                           const float* __restrict__ piPre,
                                           bf16* __restrict__ yout) {
  int blk = blockIdx.x;
  int bh = blk >> 4, chunk = blk & 15;
  int b = bh >> 4, h = bh & 15;
  int d = threadIdx.x;
  const float* base =
      w + ((size_t)bh * 2048 + (size_t)chunk * 128) * 128 + d;
  const float* pib = Pi + (size_t)bh * 2048 + (size_t)chunk * 128;
  float cum = pre2[((size_t)bh * 16 + chunk) * 128 + d];
  float cpi = piPre[bh * 16 + chunk];
  for (int i = 0; i < 128; ++i) {
    float p = pib[i];
    float v = base[(size_t)i * 128];
    cum += v * v * p;
    cpi += p;
    float dots = cum / (cpi + EPS_F16);
    float attn = 1.f / (1.f + dots);
    float y = -(v * p) * attn;
    int n = chunk * 128 + i;
    yout[((size_t)(b * 2048 + n)) * 2048 + h * 128 + d] = (bf16)y;
  }
}

// ---------------- launcher ----------------
extern "C" void kernel_launch(void* const* d_in, const int* in_sizes, int n_in,
                              void* d_out, int out_size, void* d_ws, size_t ws_size,
                              hipStream_t stream) {
  const float* x     = (const float*)d_in[0];
  const float* Wa    = (const float*)d_in[1];
  const float* Wp    = (const float*)d_in[2];
  const float* temp  = (const float*)d_in[3];
  const float* dbias = (const float*)d_in[4];
  float* out = (float*)d_out;

  char* ws = (char*)d_ws;
  // workspace layout (bytes)
  constexpr size_t OFF_W   = 0;                        // w fp32 (B,H,N,D): 134217728
  constexpr size_t OFF_XH  = 134217728;                // x_hi bf16 (reused as y): 67108864
  constexpr size_t OFF_XL  = OFF_XH + 67108864;        // x_lo bf16: 67108864
  constexpr size_t OFF_WAH = OFF_XL + 67108864;        // W_attn hi bf16: 8388608
  constexpr size_t OFF_WAL = OFF_WAH + 8388608;        // W_attn lo bf16: 8388608
  constexpr size_t OFF_WPB = OFF_WAL + 8388608;        // W_proj bf16: 8388608
  constexpr size_t OFF_TMP = OFF_WPB + 8388608;        // tmp (B,H,N) fp32
  constexpr size_t OFF_PI  = OFF_TMP + 2097152;        // Pi  (B,H,N) fp32
  constexpr size_t OFF_PS  = OFF_PI + 2097152;         // chunk partials
  constexpr size_t OFF_PIS = OFF_PS + 1048576;         // Pi chunk partials

  float* w    = (float*)(ws + OFF_W);
  bf16*  xh   = (bf16*)(ws + OFF_XH);   // later reused as y (bf16)
  bf16*  xl   = (bf16*)(ws + OFF_XL);
  bf16*  Wah  = (bf16*)(ws + OFF_WAH);
  bf16*  Wal  = (bf16*)(ws + OFF_WAL);
  bf16*  Wpb  = (bf16*)(ws + OFF_WPB);
  float* tmp  = (float*)(ws + OFF_TMP);
  float* Pi   = (float*)(ws + OFF_PI);
  float* psum = (float*)(ws + OFF_PS);
  float* pis  = (float*)(ws + OFF_PIS);

  // casts
  k_cast_split<<<16384, 256, 0, stream>>>(x, xh, xl, 4194304LL);
  k_cast_split<<<2048, 256, 0, stream>>>(Wa, Wah, Wal, 524288LL);
  k_cast8<<<2048, 256, 0, stream>>>(Wp, Wpb, 524288LL);

  // GEMM1 (split precision): w = x @ W_attn^T, (B,H,N,D) layout
  gemm_split<<<dim3(16, 128), 256, 0, stream>>>(xh, xl, Wah, Wal, w);

  // scan A: denom cumsum -> tmp
  k_partial_wsq<<<2048, 128, 0, stream>>>(w, psum);
  k_prefix<<<64, 256, 0, stream>>>(psum);
  k_tmp<<<2048, 128, 0, stream>>>(w, psum, dbias, temp, tmp);

  // softmax over heads
  k_softmax<<<64, 256, 0, stream>>>(tmp, Pi);

  // scan C: cum(wsq*Pi), cum(Pi) -> y (bf16, reuses xh buffer)
  k_partial2<<<2048, 128, 0, stream>>>(w, Pi, psum, pis);
  k_prefix<<<64, 256, 0, stream>>>(psum);
  k_prefix_pi<<<1, 128, 0, stream>>>(pis);
  k_y<<<2048, 128, 0, stream>>>(w, Pi, psum, pis, xh);

  // GEMM2: out = y @ W_proj^T
  gemm_bt<<<dim3(16, 128), 256, 0, stream>>>(xh, Wpb, out);
}

// Round 3
// 571.873 us; speedup vs baseline: 1.3945x; 1.3945x over previous
//
#include <hip/hip_runtime.h>
#include <math.h>

typedef _Float16 f16;
typedef f16 f16x8 __attribute__((ext_vector_type(8)));
typedef float f32x4 __attribute__((ext_vector_type(4)));

#define EPS_F16 0.0009765625f   // jnp.finfo(float16).eps

// B=8, N=2048, C=2048, H=16, D=128, M=B*N=16384, K=C=2048

// ---------------- fp32 -> fp16 cast, 8 elems/thread ----------------
__global__ __launch_bounds__(256) void k_cast8h(const float* __restrict__ in,
                                                f16* __restrict__ out,
                                                long long n8) {
  long long i = (long long)blockIdx.x * blockDim.x + threadIdx.x;
  if (i >= n8) return;
  const float4* in4 = (const float4*)in;
  float4 a = in4[i * 2];
  float4 b = in4[i * 2 + 1];
  f16x8 o;
  o[0] = (f16)a.x; o[1] = (f16)a.y; o[2] = (f16)a.z; o[3] = (f16)a.w;
  o[4] = (f16)b.x; o[5] = (f16)b.y; o[6] = (f16)b.z; o[7] = (f16)b.w;
  *(f16x8*)(out + i * 8) = o;
}

// ---------------- async global->LDS helper ----------------
__device__ __forceinline__ void gl2lds16(const void* g, void* l) {
  __builtin_amdgcn_global_load_lds(
      (const __attribute__((address_space(1))) void*)g,
      (__attribute__((address_space(3))) void*)l, 16, 0, 0);
}

// ---------------- GEMM fp16: C = A (MxK) * Bm (NxK)^T, fp32 out ----------
// m97 structure: 128x128 tile, BK=64, 4 waves, 16x16x32 MFMA, global_load_lds.
// MODE 0: Cout row-major (M x 2048)  [final projection -> d_out]
// MODE 1: Cout in (B,H,N,D) layout   [w tensor]
template <int MODE>
__global__ __launch_bounds__(256) void gemm_f16(const f16* __restrict__ A,
                                                const f16* __restrict__ Bm,
                                                float* __restrict__ Cout) {
  constexpr int K = 2048;
  __shared__ alignas(16) f16 As[128 * 64];
  __shared__ alignas(16) f16 Bs[128 * 64];
  const int tid  = threadIdx.x;
  const int lane = tid & 63;
  const int wave = tid >> 6;
  const int wr = (wave >> 1) * 64;   // wave row offset in tile
  const int wc = (wave & 1) * 64;    // wave col offset in tile
  const size_t bm = (size_t)blockIdx.y * 128;
  const size_t bn = (size_t)blockIdx.x * 128;

  // staging: thread t loads 16B: row r0+32p, cols c0..c0+7 (linear LDS dest)
  const int r0 = tid >> 3;
  const int c0 = (tid & 7) * 8;
  const f16* Ag = A + (bm + (size_t)r0) * K + c0;
  const f16* Bg = Bm + (bn + (size_t)r0) * K + c0;

  f32x4 acc[4][4] = {};

  const int row = lane & 15;
  const int kg  = (lane >> 4) * 8;

  for (int k0 = 0; k0 < K; k0 += 64) {
#pragma unroll
    for (int p = 0; p < 4; ++p) {
      gl2lds16(Ag + (size_t)p * 32 * K + k0, &As[p * 2048 + tid * 8]);
      gl2lds16(Bg + (size_t)p * 32 * K + k0, &Bs[p * 2048 + tid * 8]);
    }
    __syncthreads();
#pragma unroll
    for (int kk = 0; kk < 64; kk += 32) {
      f16x8 af[4], bfr[4];
#pragma unroll
      for (int i = 0; i < 4; ++i)
        af[i] = *(const f16x8*)&As[(wr + i * 16 + row) * 64 + kk + kg];
#pragma unroll
      for (int j = 0; j < 4; ++j)
        bfr[j] = *(const f16x8*)&Bs[(wc + j * 16 + row) * 64 + kk + kg];
#pragma unroll
      for (int i = 0; i < 4; ++i)
#pragma unroll
        for (int j = 0; j < 4; ++j)
          acc[i][j] = __builtin_amdgcn_mfma_f32_16x16x32_f16(af[i], bfr[j],
                                                             acc[i][j], 0, 0, 0);
    }
    __syncthreads();
  }

  // C/D layout: col = lane&15, row = (lane>>4)*4 + reg  (m89/m91-verified)
  const int col = lane & 15;
  const int rb  = (lane >> 4) * 4;
#pragma unroll
  for (int i = 0; i < 4; ++i) {
#pragma unroll
    for (int j = 0; j < 4; ++j) {
#pragma unroll
      for (int r = 0; r < 4; ++r) {
        size_t gr = bm + wr + i * 16 + rb + r;   // row in (B*N)
        size_t gc = bn + wc + j * 16 + col;      // out channel o = h*128+d
        float v = acc[i][j][r];
        if (MODE == 0) {
          Cout[gr * 2048 + gc] = v;
        } else {
          // (b,h,n,d) = (gr>>11, gc>>7, gr&2047, gc&127)
          Cout[(((gr >> 11) * 16 + (gc >> 7)) * 2048 + (gr & 2047)) * 128 +
               (gc & 127)] = v;
        }
      }
    }
  }
}

// ---------------- scan pass A: chunk partial sums of w^2 ----------------
// grid: B*H*16 = 2048 blocks, 128 threads (one per d). chunk = 128 n's.
__global__ __launch_bounds__(128) void k_partial_wsq(const float* __restrict__ w,
                                                     float* __restrict__ psum) {
  int blk = blockIdx.x;  // bh*16 + chunk
  int d = threadIdx.x;
  const float* base =
      w + ((size_t)(blk >> 4) * 2048 + (size_t)(blk & 15) * 128) * 128 + d;
  float s = 0.f;
#pragma unroll 4
  for (int i = 0; i < 128; ++i) {
    float v = base[(size_t)i * 128];
    s += v * v;
  }
  psum[(size_t)blk * 128 + d] = s;
}

// exclusive prefix over the 16 chunks, per (bh,d). 16384 threads.
__global__ __launch_bounds__(256) void k_prefix(float* __restrict__ psum) {
  int idx = blockIdx.x * 256 + threadIdx.x;  // bh*128 + d
  int bh = idx >> 7, d = idx & 127;
  float run = 0.f;
#pragma unroll
  for (int c = 0; c < 16; ++c) {
    size_t o = ((size_t)bh * 16 + c) * 128 + d;
    float v = psum[o];
    psum[o] = run;
    run += v;
  }
}

// XOR-swizzled LDS index (64KB tile, conflict-free both phases)
__device__ __forceinline__ int swz(int i, int j) { return i * 128 + (j ^ (i & 31)); }

// replay chunk scan: ratio = wsq/max(cum,eps); tmp[b,h,n] = (sum_d ratio + D*bias)*temp
__global__ __launch_bounds__(128) void k_tmp(const float* __restrict__ w,
                                             const float* __restrict__ pre,
                                             const float* __restrict__ dbias,
                                             const float* __restrict__ temp,
                                             float* __restrict__ tmp) {
  __shared__ float ratio[128 * 128];
  int blk = blockIdx.x;
  int bh = blk >> 4, chunk = blk & 15;
  int h = bh & 15;
  int d = threadIdx.x;
  const float* base =
      w + ((size_t)bh * 2048 + (size_t)chunk * 128) * 128 + d;
  float cum = pre[((size_t)bh * 16 + chunk) * 128 + d];
  for (int i = 0; i < 128; ++i) {
    float v = base[(size_t)i * 128];
    float sq = v * v;
    cum += sq;
    float dn = fmaxf(cum, EPS_F16);
    ratio[swz(i, d)] = sq / dn;
  }
  __syncthreads();
  float s = 0.f;
#pragma unroll 8
  for (int j = 0; j < 128; ++j) s += ratio[swz(d, j)];
  int n = chunk * 128 + d;
  tmp[(size_t)bh * 2048 + n] = (s + 128.f * dbias[h * 2048 + n]) * temp[h];
}

// softmax over H=16 heads. 16384 threads, one per (b,n).
__global__ __launch_bounds__(256) void k_softmax(const float* __restrict__ tmp,
                                                 float* __restrict__ Pi) {
  int idx = blockIdx.x * 256 + threadIdx.x;  // b*2048 + n
  int b = idx >> 11, n = idx & 2047;
  float v[16];
  float mx = -1e30f;
#pragma unroll
  for (int h = 0; h < 16; ++h) {
    v[h] = tmp[((size_t)(b * 16 + h)) * 2048 + n];
    mx = fmaxf(mx, v[h]);
  }
  float s = 0.f;
#pragma unroll
  for (int h = 0; h < 16; ++h) {
    v[h] = expf(v[h] - mx);
    s += v[h];
  }
  float inv = 1.f / s;
#pragma unroll
  for (int h = 0; h < 16; ++h)
    Pi[((size_t)(b * 16 + h)) * 2048 + n] = v[h] * inv;
}

// pass C: chunk partials of wsq*Pi (per d) and Pi (scalar)
__global__ __launch_bounds__(128) void k_partial2(const float* __restrict__ w,
                                                  const float* __restrict__ Pi,
                                                  float* __restrict__ psum,
                                                  float* __restrict__ pisum) {
  int blk = blockIdx.x;
  int bh = blk >> 4, chunk = blk & 15;
  int d = threadIdx.x;
  const float* base =
      w + ((size_t)bh * 2048 + (size_t)chunk * 128) * 128 + d;
  const float* pib = Pi + (size_t)bh * 2048 + (size_t)chunk * 128;
  float s = 0.f, sp = 0.f;
#pragma unroll 4
  for (int i = 0; i < 128; ++i) {
    float p = pib[i];
    float v = base[(size_t)i * 128];
    s += v * v * p;
    sp += p;
  }
  psum[(size_t)blk * 128 + d] = s;
  if (d == 0) pisum[blk] = sp;
}

__global__ __launch_bounds__(128) void k_prefix_pi(float* __restrict__ pisum) {
  int bh = threadIdx.x;  // 128 = B*H
  float run = 0.f;
#pragma unroll
  for (int c = 0; c < 16; ++c) {
    int o = bh * 16 + c;
    float v = pisum[o];
    pisum[o] = run;
    run += v;
  }
}

// replay: dots = cum(wsq*Pi)/(cum(Pi)+eps); y = -(w*Pi)/(1+dots), fp16, (B,N,C) layout
__global__ __launch_bounds__(128) void k_y(const float* __restrict__ w,
                                           const float* __restrict__ Pi,
                                           const float* __restrict__ pre2,
                                           const float* __restrict__ piPre,
                                           f16* __restrict__ yout) {
  int blk = blockIdx.x;
  int bh = blk >> 4, chunk = blk & 15;
  int b = bh >> 4, h = bh & 15;
  int d = threadIdx.x;
  const float* base =
      w + ((size_t)bh * 2048 + (size_t)chunk * 128) * 128 + d;
  const float* pib = Pi + (size_t)bh * 2048 + (size_t)chunk * 128;
  float cum = pre2[((size_t)bh * 16 + chunk) * 128 + d];
  float cpi = piPre[bh * 16 + chunk];
  for (int i = 0; i < 128; ++i) {
    float p = pib[i];
    float v = base[(size_t)i * 128];
    cum += v * v * p;
    cpi += p;
    float dots = cum / (cpi + EPS_F16);
    float attn = 1.f / (1.f + dots);
    float y = -(v * p) * attn;
    int n = chunk * 128 + i;
    yout[((size_t)(b * 2048 + n)) * 2048 + h * 128 + d] = (f16)y;
  }
}

// ---------------- launcher ----------------
extern "C" void kernel_launch(void* const* d_in, const int* in_sizes, int n_in,
                              void* d_out, int out_size, void* d_ws, size_t ws_size,
                              hipStream_t stream) {
  const float* x     = (const float*)d_in[0];
  const float* Wa    = (const float*)d_in[1];
  const float* Wp    = (const float*)d_in[2];
  const float* temp  = (const float*)d_in[3];
  const float* dbias = (const float*)d_in[4];
  float* out = (float*)d_out;

  char* ws = (char*)d_ws;
  // workspace layout (bytes)
  constexpr size_t OFF_W   = 0;                        // w fp32 (B,H,N,D): 134217728
  constexpr size_t OFF_XH  = 134217728;                // x fp16 (reused as y fp16): 67108864
  constexpr size_t OFF_WAH = OFF_XH + 67108864;        // W_attn fp16: 8388608
  constexpr size_t OFF_WPB = OFF_WAH + 8388608;        // W_proj fp16: 8388608
  constexpr size_t OFF_TMP = OFF_WPB + 8388608;        // tmp (B,H,N) fp32
  constexpr size_t OFF_PI  = OFF_TMP + 2097152;        // Pi  (B,H,N) fp32
  constexpr size_t OFF_PS  = OFF_PI + 2097152;         // chunk partials
  constexpr size_t OFF_PIS = OFF_PS + 1048576;         // Pi chunk partials

  float* w    = (float*)(ws + OFF_W);
  f16*   xh   = (f16*)(ws + OFF_XH);   // later reused as y (fp16)
  f16*   Wah  = (f16*)(ws + OFF_WAH);
  f16*   Wpb  = (f16*)(ws + OFF_WPB);
  float* tmp  = (float*)(ws + OFF_TMP);
  float* Pi   = (float*)(ws + OFF_PI);
  float* psum = (float*)(ws + OFF_PS);
  float* pis  = (float*)(ws + OFF_PIS);

  // casts
  k_cast8h<<<16384, 256, 0, stream>>>(x, xh, 4194304LL);
  k_cast8h<<<2048, 256, 0, stream>>>(Wa, Wah, 524288LL);
  k_cast8h<<<2048, 256, 0, stream>>>(Wp, Wpb, 524288LL);

  // GEMM1 (fp16): w = x @ W_attn^T, (B,H,N,D) layout
  gemm_f16<1><<<dim3(16, 128), 256, 0, stream>>>(xh, Wah, w);

  // scan A: denom cumsum -> tmp
  k_partial_wsq<<<2048, 128, 0, stream>>>(w, psum);
  k_prefix<<<64, 256, 0, stream>>>(psum);
  k_tmp<<<2048, 128, 0, stream>>>(w, psum, dbias, temp, tmp);

  // softmax over heads
  k_softmax<<<64, 256, 0, stream>>>(tmp, Pi);

  // scan C: cum(wsq*Pi), cum(Pi) -> y (fp16, reuses xh buffer)
  k_partial2<<<2048, 128, 0, stream>>>(w, Pi, psum, pis);
  k_prefix<<<64, 256, 0, stream>>>(psum);
  k_prefix_pi<<<1, 128, 0, stream>>>(pis);
  k_y<<<2048, 128, 0, stream>>>(w, Pi, psum, pis, xh);

  // GEMM2 (fp16): out = y @ W_proj^T
  gemm_f16<0><<<dim3(16, 128), 256, 0, stream>>>(xh, Wpb, out);
}

// Round 5
// 450.837 us; speedup vs baseline: 1.7688x; 1.2685x over previous
//
#include <hip/hip_runtime.h>
#include <math.h>

typedef _Float16 f16;
typedef f16 f16x8 __attribute__((ext_vector_type(8)));
typedef float f32x4 __attribute__((ext_vector_type(4)));

#define EPS_F16 0.0009765625f   // jnp.finfo(float16).eps

// B=8, N=2048, C=2048, H=16, D=128, M=B*N=16384, K=C=2048

// ---------------- fp32 -> fp16 cast, 8 elems/thread ----------------
__global__ __launch_bounds__(256) void k_cast8h(const float* __restrict__ in,
                                                f16* __restrict__ out,
                                                long long n8) {
  long long i = (long long)blockIdx.x * blockDim.x + threadIdx.x;
  if (i >= n8) return;
  const float4* in4 = (const float4*)in;
  float4 a = in4[i * 2];
  float4 b = in4[i * 2 + 1];
  f16x8 o;
  o[0] = (f16)a.x; o[1] = (f16)a.y; o[2] = (f16)a.z; o[3] = (f16)a.w;
  o[4] = (f16)b.x; o[5] = (f16)b.y; o[6] = (f16)b.z; o[7] = (f16)b.w;
  *(f16x8*)(out + i * 8) = o;
}

// ---------------- async global->LDS helper ----------------
__device__ __forceinline__ void gl2lds16(const void* g, void* l) {
  __builtin_amdgcn_global_load_lds(
      (const __attribute__((address_space(1))) void*)g,
      (__attribute__((address_space(3))) void*)l, 16, 0, 0);
}

// full drain + scheduling fence + barrier (explicit: do NOT trust the
// compiler's pre-barrier waitcnt insertion for runtime-addressed LDS-DMA)
__device__ __forceinline__ void drain_barrier() {
  asm volatile("s_waitcnt vmcnt(0) lgkmcnt(0)" ::: "memory");
  __builtin_amdgcn_sched_barrier(0);
  __syncthreads();
}

// ============ 256x256 tile GEMM, BK=64, 8 waves, dbuf LDS + st_16x32 swizzle ====
// C = A (MxK) * Bm (NxK)^T, fp16 in, fp32 out. K=2048.
// MODE 0: Cout row-major (M x 2048)           [final projection]
// MODE 1: Cout in (B,H,N,D) layout + fused chunk partial sums of w^2 into psum
template <int MODE>
__global__ __launch_bounds__(512, 2) void gemm256(const f16* __restrict__ A,
                                                  const f16* __restrict__ Bm,
                                                  float* __restrict__ Cout,
                                                  float* __restrict__ psum) {
  constexpr int K = 2048;
  __shared__ alignas(16) char lds[131072];
  const int t = threadIdx.x;
  const int lane = t & 63;
  const int wid = t >> 6;
  const int wm = wid >> 2;   // M-half owner (0..1)
  const int wn = wid & 3;    // N-quarter owner (0..3)
  const size_t bm = (size_t)blockIdx.y * 256;
  const size_t bn = (size_t)blockIdx.x * 256;

  // staging source geometry: thread t, chunk j writes LDS bytes [j*8192+t*16,+16);
  // source element = involution of that physical position (st_16x32 swizzle).
  size_t aOff[4], bOff[4];
  int sp[4];
#pragma unroll
  for (int j = 0; j < 4; ++j) {
    int sr = j * 64 + (t >> 7) * 16 + ((t & 63) >> 2);
    int sc = ((t >> 6) & 1) * 32 + (((t & 3) * 8) ^ (((t >> 5) & 1) << 4));
    sp[j] = j * 8192 + t * 16;
    aOff[j] = (bm + (size_t)sr) * K + sc;
    bOff[j] = (bn + (size_t)sr) * K + sc;
  }

  // per-lane fragment byte offset within a subtile (same XOR involution)
  const int lbyte = (((lane & 15) * 64 + (lane >> 4) * 16) ^ ((lane & 8) << 2));

  f32x4 acc[8][4] = {};

  // prologue: stage K-tile 0 into slot 0
#pragma unroll
  for (int j = 0; j < 4; ++j) {
    gl2lds16(A + aOff[j], lds + sp[j]);
    gl2lds16(Bm + bOff[j], lds + 32768 + sp[j]);
  }
  drain_barrier();

  int s = 0;
  for (int kt = 0; kt < K / 64; ++kt) {
    // prefetch next K-tile into the other slot (its readers finished before
    // the previous drain_barrier; its data is needed only after the next one)
    if (kt + 1 < K / 64) {
      const int ns = s ^ 1;
      const size_t ko = (size_t)(kt + 1) * 64;
#pragma unroll
      for (int j = 0; j < 4; ++j) {
        gl2lds16(A + aOff[j] + ko, lds + ns * 65536 + sp[j]);
        gl2lds16(Bm + bOff[j] + ko, lds + ns * 65536 + 32768 + sp[j]);
      }
    }
    // compute current tile: 4 quadrant phases (2 Mfrag x 4 Nfrag x 2 k-steps)
    const char* Ab = lds + s * 65536 + wm * 16384 + lbyte;
    const char* Bb = lds + s * 65536 + 32768 + wn * 8192 + lbyte;
    f16x8 bfrag[4][2];
#pragma unroll
    for (int q = 0; q < 4; ++q) {
      if (q == 0) {
#pragma unroll
        for (int fj = 0; fj < 4; ++fj)
#pragma unroll
          for (int k2 = 0; k2 < 2; ++k2)
            bfrag[fj][k2] = *(const f16x8*)(Bb + (fj * 2 + k2) * 1024);
      }
      f16x8 afrag[2][2];
#pragma unroll
      for (int mi = 0; mi < 2; ++mi)
#pragma unroll
        for (int k2 = 0; k2 < 2; ++k2)
          afrag[mi][k2] = *(const f16x8*)(Ab + ((q * 2 + mi) * 2 + k2) * 1024);
#pragma unroll
      for (int mi = 0; mi < 2; ++mi)
#pragma unroll
        for (int fj = 0; fj < 4; ++fj)
#pragma unroll
          for (int k2 = 0; k2 < 2; ++k2)
            acc[q * 2 + mi][fj] = __builtin_amdgcn_mfma_f32_16x16x32_f16(
                afrag[mi][k2], bfrag[fj][k2], acc[q * 2 + mi][fj], 0, 0, 0);
    }
    drain_barrier();   // prefetch landed + all reads of slot s done, for ALL waves
    s ^= 1;
  }

  // ---- epilogue ----
  const int col = lane & 15;
  const int rb = (lane >> 4) * 4;
#pragma unroll
  for (int fi = 0; fi < 8; ++fi)
#pragma unroll
    for (int fj = 0; fj < 4; ++fj)
#pragma unroll
      for (int r = 0; r < 4; ++r) {
        size_t gr = bm + wm * 128 + fi * 16 + rb + r;   // row in (B*N)
        size_t gc = bn + wn * 64 + fj * 16 + col;       // out channel
        float v = acc[fi][fj][r];
        if constexpr (MODE == 0) {
          Cout[gr * 2048 + gc] = v;
        } else {
          // (b,h,n,d) = (gr>>11, gc>>7, gr&2047, gc&127)
          Cout[(((gr >> 11) * 16 + (gc >> 7)) * 2048 + (gr & 2047)) * 128 +
               (gc & 127)] = v;
        }
      }
  if constexpr (MODE == 1) {
    // fused chunk partials: this wave's 128 rows = exactly one chunk of 128 n's
#pragma unroll
    for (int fj = 0; fj < 4; ++fj) {
      float ss = 0.f;
#pragma unroll
      for (int fi = 0; fi < 8; ++fi)
#pragma unroll
        for (int r = 0; r < 4; ++r) ss += acc[fi][fj][r] * acc[fi][fj][r];
      ss += __shfl_xor(ss, 16);
      ss += __shfl_xor(ss, 32);
      if (lane < 16) {
        int b = (int)(bm >> 11);                    // by>>3
        int h = (int)(bn >> 7) + (wn >> 1);         // bx*2 + wn>>1
        int chunk = (int)((bm & 2047) >> 7) + wm;   // (by&7)*2 + wm
        int d = (wn & 1) * 64 + fj * 16 + lane;
        psum[(((size_t)(b * 16 + h)) * 16 + chunk) * 128 + d] = ss;
      }
    }
  }
}

// exclusive prefix over the 16 chunks, per (bh,d). 16384 threads.
__global__ __launch_bounds__(256) void k_prefix(float* __restrict__ psum) {
  int idx = blockIdx.x * 256 + threadIdx.x;  // bh*128 + d
  int bh = idx >> 7, d = idx & 127;
  float run = 0.f;
#pragma unroll
  for (int c = 0; c < 16; ++c) {
    size_t o = ((size_t)bh * 16 + c) * 128 + d;
    float v = psum[o];
    psum[o] = run;
    run += v;
  }
}

// XOR-swizzled LDS index (64KB tile, conflict-free both phases)
__device__ __forceinline__ int swz(int i, int j) { return i * 128 + (j ^ (i & 31)); }

// replay chunk scan: ratio = wsq/max(cum,eps); tmp[b,h,n] = (sum_d ratio + D*bias)*temp
__global__ __launch_bounds__(128) void k_tmp(const float* __restrict__ w,
                                             const float* __restrict__ pre,
                                             const float* __restrict__ dbias,
                                             const float* __restrict__ temp,
                                             float* __restrict__ tmp) {
  __shared__ float ratio[128 * 128];
  int blk = blockIdx.x;
  int bh = blk >> 4, chunk = blk & 15;
  int h = bh & 15;
  int d = threadIdx.x;
  const float* base =
      w + ((size_t)bh * 2048 + (size_t)chunk * 128) * 128 + d;
  float cum = pre[((size_t)bh * 16 + chunk) * 128 + d];
  for (int i = 0; i < 128; ++i) {
    float v = base[(size_t)i * 128];
    float sq = v * v;
    cum += sq;
    float dn = fmaxf(cum, EPS_F16);
    ratio[swz(i, d)] = sq / dn;
  }
  __syncthreads();
  float s = 0.f;
#pragma unroll 8
  for (int j = 0; j < 128; ++j) s += ratio[swz(d, j)];
  int n = chunk * 128 + d;
  tmp[(size_t)bh * 2048 + n] = (s + 128.f * dbias[h * 2048 + n]) * temp[h];
}

// softmax over H=16 heads. 16384 threads, one per (b,n).
__global__ __launch_bounds__(256) void k_softmax(const float* __restrict__ tmp,
                                                 float* __restrict__ Pi) {
  int idx = blockIdx.x * 256 + threadIdx.x;  // b*2048 + n
  int b = idx >> 11, n = idx & 2047;
  float v[16];
  float mx = -1e30f;
#pragma unroll
  for (int h = 0; h < 16; ++h) {
    v[h] = tmp[((size_t)(b * 16 + h)) * 2048 + n];
    mx = fmaxf(mx, v[h]);
  }
  float s = 0.f;
#pragma unroll
  for (int h = 0; h < 16; ++h) {
    v[h] = expf(v[h] - mx);
    s += v[h];
  }
  float inv = 1.f / s;
#pragma unroll
  for (int h = 0; h < 16; ++h)
    Pi[((size_t)(b * 16 + h)) * 2048 + n] = v[h] * inv;
}

// pass C: chunk partials of wsq*Pi (per d) and Pi (scalar)
__global__ __launch_bounds__(128) void k_partial2(const float* __restrict__ w,
                                                  const float* __restrict__ Pi,
                                                  float* __restrict__ psum,
                                                  float* __restrict__ pisum) {
  int blk = blockIdx.x;
  int bh = blk >> 4, chunk = blk & 15;
  int d = threadIdx.x;
  const float* base =
      w + ((size_t)bh * 2048 + (size_t)chunk * 128) * 128 + d;
  const float* pib = Pi + (size_t)bh * 2048 + (size_t)chunk * 128;
  float s = 0.f, sp = 0.f;
#pragma unroll 4
  for (int i = 0; i < 128; ++i) {
    float p = pib[i];
    float v = base[(size_t)i * 128];
    s += v * v * p;
    sp += p;
  }
  psum[(size_t)blk * 128 + d] = s;
  if (d == 0) pisum[blk] = sp;
}

__global__ __launch_bounds__(128) void k_prefix_pi(float* __restrict__ pisum) {
  int bh = threadIdx.x;  // 128 = B*H
  float run = 0.f;
#pragma unroll
  for (int c = 0; c < 16; ++c) {
    int o = bh * 16 + c;
    float v = pisum[o];
    pisum[o] = run;
    run += v;
  }
}

// replay: dots = cum(wsq*Pi)/(cum(Pi)+eps); y = -(w*Pi)/(1+dots), fp16, (B,N,C) layout
__global__ __launch_bounds__(128) void k_y(const float* __restrict__ w,
                                           const float* __restrict__ Pi,
                                           const float* __restrict__ pre2,
                                           const float* __restrict__ piPre,
                                           f16* __restrict__ yout) {
  int blk = blockIdx.x;
  int bh = blk >> 4, chunk = blk & 15;
  int b = bh >> 4, h = bh & 15;
  int d = threadIdx.x;
  const float* base =
      w + ((size_t)bh * 2048 + (size_t)chunk * 128) * 128 + d;
  const float* pib = Pi + (size_t)bh * 2048 + (size_t)chunk * 128;
  float cum = pre2[((size_t)bh * 16 + chunk) * 128 + d];
  float cpi = piPre[bh * 16 + chunk];
  for (int i = 0; i < 128; ++i) {
    float p = pib[i];
    float v = base[(size_t)i * 128];
    cum += v * v * p;
    cpi += p;
    float dots = cum / (cpi + EPS_F16);
    float attn = 1.f / (1.f + dots);
    float y = -(v * p) * attn;
    int n = chunk * 128 + i;
    yout[((size_t)(b * 2048 + n)) * 2048 + h * 128 + d] = (f16)y;
  }
}

// ---------------- launcher ----------------
extern "C" void kernel_launch(void* const* d_in, const int* in_sizes, int n_in,
                              void* d_out, int out_size, void* d_ws, size_t ws_size,
                              hipStream_t stream) {
  const float* x     = (const float*)d_in[0];
  const float* Wa    = (const float*)d_in[1];
  const float* Wp    = (const float*)d_in[2];
  const float* temp  = (const float*)d_in[3];
  const float* dbias = (const float*)d_in[4];
  float* out = (float*)d_out;

  char* ws = (char*)d_ws;
  // workspace layout (bytes)
  constexpr size_t OFF_W   = 0;                        // w fp32 (B,H,N,D): 134217728
  constexpr size_t OFF_XH  = 134217728;                // x fp16 (reused as y fp16): 67108864
  constexpr size_t OFF_WAH = OFF_XH + 67108864;        // W_attn fp16: 8388608
  constexpr size_t OFF_WPB = OFF_WAH + 8388608;        // W_proj fp16: 8388608
  constexpr size_t OFF_TMP = OFF_WPB + 8388608;        // tmp (B,H,N) fp32
  constexpr size_t OFF_PI  = OFF_TMP + 2097152;        // Pi  (B,H,N) fp32
  constexpr size_t OFF_PS  = OFF_PI + 2097152;         // chunk partials
  constexpr size_t OFF_PIS = OFF_PS + 1048576;         // Pi chunk partials

  float* w    = (float*)(ws + OFF_W);
  f16*   xh   = (f16*)(ws + OFF_XH);   // later reused as y (fp16)
  f16*   Wah  = (f16*)(ws + OFF_WAH);
  f16*   Wpb  = (f16*)(ws + OFF_WPB);
  float* tmp  = (float*)(ws + OFF_TMP);
  float* Pi   = (float*)(ws + OFF_PI);
  float* psum = (float*)(ws + OFF_PS);
  float* pis  = (float*)(ws + OFF_PIS);

  // casts
  k_cast8h<<<16384, 256, 0, stream>>>(x, xh, 4194304LL);
  k_cast8h<<<2048, 256, 0, stream>>>(Wa, Wah, 524288LL);
  k_cast8h<<<2048, 256, 0, stream>>>(Wp, Wpb, 524288LL);

  // GEMM1 (fp16, 256^2 tile): w = x @ W_attn^T, (B,H,N,D) layout + fused wsq partials
  gemm256<1><<<dim3(8, 64), 512, 0, stream>>>(xh, Wah, w, psum);

  // scan A: prefix of chunk partials -> tmp
  k_prefix<<<64, 256, 0, stream>>>(psum);
  k_tmp<<<2048, 128, 0, stream>>>(w, psum, dbias, temp, tmp);

  // softmax over heads
  k_softmax<<<64, 256, 0, stream>>>(tmp, Pi);

  // scan C: cum(wsq*Pi), cum(Pi) -> y (fp16, reuses xh buffer)
  k_partial2<<<2048, 128, 0, stream>>>(w, Pi, psum, pis);
  k_prefix<<<64, 256, 0, stream>>>(psum);
  k_prefix_pi<<<1, 128, 0, stream>>>(pis);
  k_y<<<2048, 128, 0, stream>>>(w, Pi, psum, pis, xh);

  // GEMM2 (fp16, 256^2 tile): out = y @ W_proj^T
  gemm256<0><<<dim3(8, 64), 512, 0, stream>>>(xh, Wpb, out, nullptr);
}

// Round 6
// 445.481 us; speedup vs baseline: 1.7901x; 1.0120x over previous
//
#include <hip/hip_runtime.h>
#include <math.h>

typedef _Float16 f16;
typedef f16 f16x8 __attribute__((ext_vector_type(8)));
typedef float f32x4 __attribute__((ext_vector_type(4)));

#define EPS_F16 0.0009765625f   // jnp.finfo(float16).eps

// B=8, N=2048, C=2048, H=16, D=128, M=B*N=16384, K=C=2048

// ---------------- fp32 -> fp16 cast, 8 elems/thread ----------------
__global__ __launch_bounds__(256) void k_cast8h(const float* __restrict__ in,
                                                f16* __restrict__ out,
                                                long long n8) {
  long long i = (long long)blockIdx.x * blockDim.x + threadIdx.x;
  if (i >= n8) return;
  const float4* in4 = (const float4*)in;
  float4 a = in4[i * 2];
  float4 b = in4[i * 2 + 1];
  f16x8 o;
  o[0] = (f16)a.x; o[1] = (f16)a.y; o[2] = (f16)a.z; o[3] = (f16)a.w;
  o[4] = (f16)b.x; o[5] = (f16)b.y; o[6] = (f16)b.z; o[7] = (f16)b.w;
  *(f16x8*)(out + i * 8) = o;
}

// ---------------- async global->LDS helper ----------------
__device__ __forceinline__ void gl2lds16(const void* g, void* l) {
  __builtin_amdgcn_global_load_lds(
      (const __attribute__((address_space(1))) void*)g,
      (__attribute__((address_space(3))) void*)l, 16, 0, 0);
}

// full drain + scheduling fence + barrier (explicit: do NOT trust the
// compiler's pre-barrier waitcnt insertion for runtime-addressed LDS-DMA)
__device__ __forceinline__ void drain_barrier() {
  asm volatile("s_waitcnt vmcnt(0) lgkmcnt(0)" ::: "memory");
  __builtin_amdgcn_sched_barrier(0);
  __syncthreads();
}

// ============ 256x256 tile GEMM, BK=64, 8 waves, dbuf LDS + st_16x32 swizzle ====
// C = A (MxK) * Bm (NxK)^T, fp16 in. K=2048. Grid must be dim3(8, 64).
// MODE 0: Cout (fp32) row-major M x 2048          [final projection]
// MODE 1: Wout (fp16) in (B,H,N,D) layout + fused chunk partials of w^2 -> psum
//         (psum uses the fp16-QUANTIZED w so the scan section is an exact
//          function of the stored q = fp16(w))
template <int MODE>
__global__ __launch_bounds__(512, 2) void gemm256(const f16* __restrict__ A,
                                                  const f16* __restrict__ Bm,
                                                  float* __restrict__ Cout,
                                                  f16* __restrict__ Wout,
                                                  float* __restrict__ psum) {
  constexpr int K = 2048;
  __shared__ alignas(16) char lds[131072];
  const int t = threadIdx.x;
  const int lane = t & 63;
  const int wid = t >> 6;
  const int wm = wid >> 2;   // M-half owner (0..1)
  const int wn = wid & 3;    // N-quarter owner (0..3)

  // T1: XCD-aware chunked swizzle (bijective: 512 % 8 == 0). Hardware
  // round-robins linear id over 8 XCDs; remap so each XCD gets 64
  // consecutive logical blocks (8 full A-panel groups -> L2 reuse).
  const int lin = blockIdx.y * 8 + blockIdx.x;     // gridDim.x == 8
  const int logical = (lin & 7) * 64 + (lin >> 3);
  const size_t bm = (size_t)(logical >> 3) * 256;
  const size_t bn = (size_t)(logical & 7) * 256;

  // staging source geometry: thread t, chunk j writes LDS bytes [j*8192+t*16,+16);
  // source element = involution of that physical position (st_16x32 swizzle).
  size_t aOff[4], bOff[4];
  int sp[4];
#pragma unroll
  for (int j = 0; j < 4; ++j) {
    int sr = j * 64 + (t >> 7) * 16 + ((t & 63) >> 2);
    int sc = ((t >> 6) & 1) * 32 + (((t & 3) * 8) ^ (((t >> 5) & 1) << 4));
    sp[j] = j * 8192 + t * 16;
    aOff[j] = (bm + (size_t)sr) * K + sc;
    bOff[j] = (bn + (size_t)sr) * K + sc;
  }

  // per-lane fragment byte offset within a subtile (same XOR involution)
  const int lbyte = (((lane & 15) * 64 + (lane >> 4) * 16) ^ ((lane & 8) << 2));

  f32x4 acc[8][4] = {};

  // prologue: stage K-tile 0 into slot 0
#pragma unroll
  for (int j = 0; j < 4; ++j) {
    gl2lds16(A + aOff[j], lds + sp[j]);
    gl2lds16(Bm + bOff[j], lds + 32768 + sp[j]);
  }
  drain_barrier();

  int s = 0;
  for (int kt = 0; kt < K / 64; ++kt) {
    // prefetch next K-tile into the other slot (its readers finished before
    // the previous drain_barrier; its data is needed only after the next one)
    if (kt + 1 < K / 64) {
      const int ns = s ^ 1;
      const size_t ko = (size_t)(kt + 1) * 64;
#pragma unroll
      for (int j = 0; j < 4; ++j) {
        gl2lds16(A + aOff[j] + ko, lds + ns * 65536 + sp[j]);
        gl2lds16(Bm + bOff[j] + ko, lds + ns * 65536 + 32768 + sp[j]);
      }
    }
    // compute current tile: 4 quadrant phases (2 Mfrag x 4 Nfrag x 2 k-steps)
    const char* Ab = lds + s * 65536 + wm * 16384 + lbyte;
    const char* Bb = lds + s * 65536 + 32768 + wn * 8192 + lbyte;
    f16x8 bfrag[4][2];
#pragma unroll
    for (int q = 0; q < 4; ++q) {
      if (q == 0) {
#pragma unroll
        for (int fj = 0; fj < 4; ++fj)
#pragma unroll
          for (int k2 = 0; k2 < 2; ++k2)
            bfrag[fj][k2] = *(const f16x8*)(Bb + (fj * 2 + k2) * 1024);
      }
      f16x8 afrag[2][2];
#pragma unroll
      for (int mi = 0; mi < 2; ++mi)
#pragma unroll
        for (int k2 = 0; k2 < 2; ++k2)
          afrag[mi][k2] = *(const f16x8*)(Ab + ((q * 2 + mi) * 2 + k2) * 1024);
#pragma unroll
      for (int mi = 0; mi < 2; ++mi)
#pragma unroll
        for (int fj = 0; fj < 4; ++fj)
#pragma unroll
          for (int k2 = 0; k2 < 2; ++k2)
            acc[q * 2 + mi][fj] = __builtin_amdgcn_mfma_f32_16x16x32_f16(
                afrag[mi][k2], bfrag[fj][k2], acc[q * 2 + mi][fj], 0, 0, 0);
    }
    drain_barrier();   // prefetch landed + all reads of slot s done, for ALL waves
    s ^= 1;
  }

  // ---- epilogue ----
  const int col = lane & 15;
  const int rb = (lane >> 4) * 4;
  if constexpr (MODE == 0) {
#pragma unroll
    for (int fi = 0; fi < 8; ++fi)
#pragma unroll
      for (int fj = 0; fj < 4; ++fj)
#pragma unroll
        for (int r = 0; r < 4; ++r) {
          size_t gr = bm + wm * 128 + fi * 16 + rb + r;   // row in (B*N)
          size_t gc = bn + wn * 64 + fj * 16 + col;       // out channel
          Cout[gr * 2048 + gc] = acc[fi][fj][r];
        }
  } else {
    // write q = fp16(w) in (B,H,N,D) layout; accumulate chunk partials of q^2
#pragma unroll
    for (int fj = 0; fj < 4; ++fj) {
      float ss = 0.f;
#pragma unroll
      for (int fi = 0; fi < 8; ++fi)
#pragma unroll
        for (int r = 0; r < 4; ++r) {
          size_t gr = bm + wm * 128 + fi * 16 + rb + r;   // row in (B*N)
          size_t gc = bn + wn * 64 + fj * 16 + col;       // out channel
          f16 q = (f16)acc[fi][fj][r];
          // (b,h,n,d) = (gr>>11, gc>>7, gr&2047, gc&127)
          Wout[(((gr >> 11) * 16 + (gc >> 7)) * 2048 + (gr & 2047)) * 128 +
               (gc & 127)] = q;
          float qf = (float)q;
          ss += qf * qf;
        }
      ss += __shfl_xor(ss, 16);
      ss += __shfl_xor(ss, 32);
      if (lane < 16) {
        int b = (int)(bm >> 11);                    // logical_y>>3
        int h = (int)(bn >> 7) + (wn >> 1);         // logical_x*2 + wn>>1
        int chunk = (int)((bm & 2047) >> 7) + wm;   // (logical_y&7)*2 + wm
        int d = (wn & 1) * 64 + fj * 16 + lane;
        psum[(((size_t)(b * 16 + h)) * 16 + chunk) * 128 + d] = ss;
      }
    }
  }
}

// exclusive prefix over the 16 chunks, per (bh,d). 16384 threads.
__global__ __launch_bounds__(256) void k_prefix(float* __restrict__ psum) {
  int idx = blockIdx.x * 256 + threadIdx.x;  // bh*128 + d
  int bh = idx >> 7, d = idx & 127;
  float run = 0.f;
#pragma unroll
  for (int c = 0; c < 16; ++c) {
    size_t o = ((size_t)bh * 16 + c) * 128 + d;
    float v = psum[o];
    psum[o] = run;
    run += v;
  }
}

// XOR-swizzled LDS index (64KB tile, conflict-free both phases)
__device__ __forceinline__ int swz(int i, int j) { return i * 128 + (j ^ (i & 31)); }

// replay chunk scan: ratio = q^2/max(cum,eps); tmp[b,h,n] = (sum_d ratio + D*bias)*temp
__global__ __launch_bounds__(128) void k_tmp(const f16* __restrict__ w,
                                             const float* __restrict__ pre,
                                             const float* __restrict__ dbias,
                                             const float* __restrict__ temp,
                                             float* __restrict__ tmp) {
  __shared__ float ratio[128 * 128];
  int blk = blockIdx.x;
  int bh = blk >> 4, chunk = blk & 15;
  int h = bh & 15;
  int d = threadIdx.x;
  const f16* base =
      w + ((size_t)bh * 2048 + (size_t)chunk * 128) * 128 + d;
  float cum = pre[((size_t)bh * 16 + chunk) * 128 + d];
  for (int i = 0; i < 128; ++i) {
    float v = (float)base[(size_t)i * 128];
    float sq = v * v;
    cum += sq;
    float dn = fmaxf(cum, EPS_F16);
    ratio[swz(i, d)] = sq / dn;
  }
  __syncthreads();
  float s = 0.f;
#pragma unroll 8
  for (int j = 0; j < 128; ++j) s += ratio[swz(d, j)];
  int n = chunk * 128 + d;
  tmp[(size_t)bh * 2048 + n] = (s + 128.f * dbias[h * 2048 + n]) * temp[h];
}

// softmax over H=16 heads. 16384 threads, one per (b,n).
__global__ __launch_bounds__(256) void k_softmax(const float* __restrict__ tmp,
                                                 float* __restrict__ Pi) {
  int idx = blockIdx.x * 256 + threadIdx.x;  // b*2048 + n
  int b = idx >> 11, n = idx & 2047;
  float v[16];
  float mx = -1e30f;
#pragma unroll
  for (int h = 0; h < 16; ++h) {
    v[h] = tmp[((size_t)(b * 16 + h)) * 2048 + n];
    mx = fmaxf(mx, v[h]);
  }
  float s = 0.f;
#pragma unroll
  for (int h = 0; h < 16; ++h) {
    v[h] = expf(v[h] - mx);
    s += v[h];
  }
  float inv = 1.f / s;
#pragma unroll
  for (int h = 0; h < 16; ++h)
    Pi[((size_t)(b * 16 + h)) * 2048 + n] = v[h] * inv;
}

// pass C: chunk partials of q^2*Pi (per d) and Pi (scalar)
__global__ __launch_bounds__(128) void k_partial2(const f16* __restrict__ w,
                                                  const float* __restrict__ Pi,
                                                  float* __restrict__ psum,
                                                  float* __restrict__ pisum) {
  int blk = blockIdx.x;
  int bh = blk >> 4, chunk = blk & 15;
  int d = threadIdx.x;
  const f16* base =
      w + ((size_t)bh * 2048 + (size_t)chunk * 128) * 128 + d;
  const float* pib = Pi + (size_t)bh * 2048 + (size_t)chunk * 128;
  float s = 0.f, sp = 0.f;
#pragma unroll 4
  for (int i = 0; i < 128; ++i) {
    float p = pib[i];
    float v = (float)base[(size_t)i * 128];
    s += v * v * p;
    sp += p;
  }
  psum[(size_t)blk * 128 + d] = s;
  if (d == 0) pisum[blk] = sp;
}

__global__ __launch_bounds__(128) void k_prefix_pi(float* __restrict__ pisum) {
  int bh = threadIdx.x;  // 128 = B*H
  float run = 0.f;
#pragma unroll
  for (int c = 0; c < 16; ++c) {
    int o = bh * 16 + c;
    float v = pisum[o];
    pisum[o] = run;
    run += v;
  }
}

// replay: dots = cum(q^2*Pi)/(cum(Pi)+eps); y = -(q*Pi)/(1+dots), fp16, (B,N,C)
__global__ __launch_bounds__(128) void k_y(const f16* __restrict__ w,
                                           const float* __restrict__ Pi,
                                           const float* __restrict__ pre2,
                                           const float* __restrict__ piPre,
                                           f16* __restrict__ yout) {
  int blk = blockIdx.x;
  int bh = blk >> 4, chunk = blk & 15;
  int b = bh >> 4, h = bh & 15;
  int d = threadIdx.x;
  const f16* base =
      w + ((size_t)bh * 2048 + (size_t)chunk * 128) * 128 + d;
  const float* pib = Pi + (size_t)bh * 2048 + (size_t)chunk * 128;
  float cum = pre2[((size_t)bh * 16 + chunk) * 128 + d];
  float cpi = piPre[bh * 16 + chunk];
  for (int i = 0; i < 128; ++i) {
    float p = pib[i];
    float v = (float)base[(size_t)i * 128];
    cum += v * v * p;
    cpi += p;
    float dots = cum / (cpi + EPS_F16);
    float attn = 1.f / (1.f + dots);
    float y = -(v * p) * attn;
    int n = chunk * 128 + i;
    yout[((size_t)(b * 2048 + n)) * 2048 + h * 128 + d] = (f16)y;
  }
}

// ---------------- launcher ----------------
extern "C" void kernel_launch(void* const* d_in, const int* in_sizes, int n_in,
                              void* d_out, int out_size, void* d_ws, size_t ws_size,
                              hipStream_t stream) {
  const float* x     = (const float*)d_in[0];
  const float* Wa    = (const float*)d_in[1];
  const float* Wp    = (const float*)d_in[2];
  const float* temp  = (const float*)d_in[3];
  const float* dbias = (const float*)d_in[4];
  float* out = (float*)d_out;

  char* ws = (char*)d_ws;
  // workspace layout (bytes)
  constexpr size_t OFF_W   = 0;                        // w fp16 (B,H,N,D): 67108864
  constexpr size_t OFF_XH  = 67108864;                 // x fp16 (reused as y fp16): 67108864
  constexpr size_t OFF_WAH = OFF_XH + 67108864;        // W_attn fp16: 8388608
  constexpr size_t OFF_WPB = OFF_WAH + 8388608;        // W_proj fp16: 8388608
  constexpr size_t OFF_TMP = OFF_WPB + 8388608;        // tmp (B,H,N) fp32
  constexpr size_t OFF_PI  = OFF_TMP + 2097152;        // Pi  (B,H,N) fp32
  constexpr size_t OFF_PS  = OFF_PI + 2097152;         // chunk partials
  constexpr size_t OFF_PIS = OFF_PS + 1048576;         // Pi chunk partials

  f16*   w    = (f16*)(ws + OFF_W);
  f16*   xh   = (f16*)(ws + OFF_XH);   // later reused as y (fp16)
  f16*   Wah  = (f16*)(ws + OFF_WAH);
  f16*   Wpb  = (f16*)(ws + OFF_WPB);
  float* tmp  = (float*)(ws + OFF_TMP);
  float* Pi   = (float*)(ws + OFF_PI);
  float* psum = (float*)(ws + OFF_PS);
  float* pis  = (float*)(ws + OFF_PIS);

  // casts
  k_cast8h<<<16384, 256, 0, stream>>>(x, xh, 4194304LL);
  k_cast8h<<<2048, 256, 0, stream>>>(Wa, Wah, 524288LL);
  k_cast8h<<<2048, 256, 0, stream>>>(Wp, Wpb, 524288LL);

  // GEMM1 (fp16, 256^2 tile): w = fp16(x @ W_attn^T), (B,H,N,D) + fused q^2 partials
  gemm256<1><<<dim3(8, 64), 512, 0, stream>>>(xh, Wah, nullptr, w, psum);

  // scan A: prefix of chunk partials -> tmp
  k_prefix<<<64, 256, 0, stream>>>(psum);
  k_tmp<<<2048, 128, 0, stream>>>(w, psum, dbias, temp, tmp);

  // softmax over heads
  k_softmax<<<64, 256, 0, stream>>>(tmp, Pi);

  // scan C: cum(q^2*Pi), cum(Pi) -> y (fp16, reuses xh buffer)
  k_partial2<<<2048, 128, 0, stream>>>(w, Pi, psum, pis);
  k_prefix<<<64, 256, 0, stream>>>(psum);
  k_prefix_pi<<<1, 128, 0, stream>>>(pis);
  k_y<<<2048, 128, 0, stream>>>(w, Pi, psum, pis, xh);

  // GEMM2 (fp16, 256^2 tile): out = y @ W_proj^T
  gemm256<0><<<dim3(8, 64), 512, 0, stream>>>(xh, Wpb, out, nullptr, nullptr);
}

// Round 8
// 440.160 us; speedup vs baseline: 1.8118x; 1.0121x over previous
//
#include <hip/hip_runtime.h>
#include <math.h>

typedef _Float16 f16;
typedef f16 f16x8 __attribute__((ext_vector_type(8)));
typedef float f32x4 __attribute__((ext_vector_type(4)));

#define EPS_F16 0.0009765625f   // jnp.finfo(float16).eps

// B=8, N=2048, C=2048, H=16, D=128, M=B*N=16384, K=C=2048

// ---------------- fp32 -> fp16 cast, 8 elems/thread ----------------
__global__ __launch_bounds__(256) void k_cast8h(const float* __restrict__ in,
                                                f16* __restrict__ out,
                                                long long n8) {
  long long i = (long long)blockIdx.x * blockDim.x + threadIdx.x;
  if (i >= n8) return;
  const float4* in4 = (const float4*)in;
  float4 a = in4[i * 2];
  float4 b = in4[i * 2 + 1];
  f16x8 o;
  o[0] = (f16)a.x; o[1] = (f16)a.y; o[2] = (f16)a.z; o[3] = (f16)a.w;
  o[4] = (f16)b.x; o[5] = (f16)b.y; o[6] = (f16)b.z; o[7] = (f16)b.w;
  *(f16x8*)(out + i * 8) = o;
}

// ---------------- async global->LDS helper ----------------
__device__ __forceinline__ void gl2lds16(const void* g, void* l) {
  __builtin_amdgcn_global_load_lds(
      (const __attribute__((address_space(1))) void*)g,
      (__attribute__((address_space(3))) void*)l, 16, 0, 0);
}

// counted vmcnt wait + scheduling fence (NEVER drain to 0 in the main loop)
template <int VM>
__device__ __forceinline__ void wait_vm() {
  if constexpr (VM == 8)      asm volatile("s_waitcnt vmcnt(8)" ::: "memory");
  else if constexpr (VM == 4) asm volatile("s_waitcnt vmcnt(4)" ::: "memory");
  else                        asm volatile("s_waitcnt vmcnt(0)" ::: "memory");
  __builtin_amdgcn_sched_barrier(0);
}

// raw barrier with compiler memory fences on both sides (plain-C ds_reads must
// not migrate across; do NOT use __syncthreads() — it drains vmcnt(0))
__device__ __forceinline__ void pipe_barrier() {
  __builtin_amdgcn_sched_barrier(0);
  asm volatile("" ::: "memory");
  __builtin_amdgcn_s_barrier();
  asm volatile("" ::: "memory");
  __builtin_amdgcn_sched_barrier(0);
}

// ====== 256x256 GEMM, BK=32, 4-slot LDS pipeline (prefetch dist 3), 8 waves ====
// C = A (MxK) * Bm (NxK)^T, fp16 in. K=2048. Grid must be dim3(8, 64).
// st_16x32 XOR swizzle on LDS (zero bank conflicts, verified r5/r6).
// Counted vmcnt(8) keeps 2 tiles of loads in flight across every barrier.
// MODE 0: Cout (fp32) row-major M x 2048          [final projection]
// MODE 1: Wout (fp16) (B,H,N,D) via LDS-transposed 128B-coalesced stores
//         + fused chunk partials of q^2 -> psum (q = fp16(w), scans exact in q)
template <int MODE>
__global__ __launch_bounds__(512, 2) void gemm256(const f16* __restrict__ A,
                                                  const f16* __restrict__ Bm,
                                                  float* __restrict__ Cout,
                                                  f16* __restrict__ Wout,
                                                  float* __restrict__ psum) {
  constexpr int K = 2048;
  constexpr int NT = K / 32;          // 64 K-tiles
  __shared__ alignas(16) char lds[131072];   // 4 slots x (A 16KB + B 16KB)
  const int t = threadIdx.x;
  const int lane = t & 63;
  const int wid = t >> 6;
  const int wm = wid >> 2;   // M-half owner (0..1)
  const int wn = wid & 3;    // N-quarter owner (0..3)

  // T1: XCD-aware chunked swizzle (bijective: 512 % 8 == 0)
  const int lin = blockIdx.y * 8 + blockIdx.x;     // gridDim.x == 8
  const int logical = (lin & 7) * 64 + (lin >> 3);
  const size_t bm = (size_t)(logical >> 3) * 256;
  const size_t bn = (size_t)(logical & 7) * 256;

  // staging source geometry (BK=32): thread t, chunk j in {0,1} writes LDS bytes
  // [j*8192 + t*16, +16) of the 16KB matrix region; source = involution image.
  const int sk = ((t & 3) * 8) ^ (((t >> 5) & 1) << 4);
  size_t aOff[2], bOff[2];
#pragma unroll
  for (int j = 0; j < 2; ++j) {
    int sr = j * 128 + (t >> 6) * 16 + ((t & 63) >> 2);
    aOff[j] = (bm + (size_t)sr) * K + sk;
    bOff[j] = (bn + (size_t)sr) * K + sk;
  }
  const int t16 = t * 16;

  // per-lane fragment byte offset within a 1024B subtile (same XOR involution)
  const int lbyte = (((lane & 15) * 64 + (lane >> 4) * 16) ^ ((lane & 8) << 2));

  f32x4 acc[8][4] = {};

  auto stage_tile = [&](int kt) {
    char* base = lds + (kt & 3) * 32768;
    const size_t ko = (size_t)kt * 32;
#pragma unroll
    for (int j = 0; j < 2; ++j) {
      gl2lds16(A + aOff[j] + ko, base + j * 8192 + t16);
      gl2lds16(Bm + bOff[j] + ko, base + 16384 + j * 8192 + t16);
    }
  };

  auto compute_tile = [&](int slot) {
    const char* Ab = lds + slot * 32768 + wm * 8192 + lbyte;
    const char* Bb = lds + slot * 32768 + 16384 + wn * 4096 + lbyte;
    f16x8 bfr[4];
#pragma unroll
    for (int fj = 0; fj < 4; ++fj) bfr[fj] = *(const f16x8*)(Bb + fj * 1024);
#pragma unroll
    for (int q = 0; q < 4; ++q) {
      f16x8 af0 = *(const f16x8*)(Ab + (q * 2) * 1024);
      f16x8 af1 = *(const f16x8*)(Ab + (q * 2 + 1) * 1024);
      __builtin_amdgcn_s_setprio(1);
#pragma unroll
      for (int fj = 0; fj < 4; ++fj) {
        acc[q * 2][fj] = __builtin_amdgcn_mfma_f32_16x16x32_f16(
            af0, bfr[fj], acc[q * 2][fj], 0, 0, 0);
        acc[q * 2 + 1][fj] = __builtin_amdgcn_mfma_f32_16x16x32_f16(
            af1, bfr[fj], acc[q * 2 + 1][fj], 0, 0, 0);
      }
      __builtin_amdgcn_s_setprio(0);
    }
  };

  // prologue: stage tiles 0,1,2 (12 loads/thread); wait tile0 (vmcnt 8 left)
  stage_tile(0);
  stage_tile(1);
  stage_tile(2);
  wait_vm<8>();
  pipe_barrier();

  // steady state: loads for tiles t+2, t+3 stay in flight across the barrier
  for (int kt = 0; kt <= NT - 4; ++kt) {
    stage_tile(kt + 3);
    compute_tile(kt & 3);
    wait_vm<8>();        // tile kt+1 landed; {kt+2, kt+3} outstanding
    pipe_barrier();
  }
  // tail: NT-3, NT-2, NT-1
  compute_tile((NT - 3) & 3); wait_vm<4>(); pipe_barrier();
  compute_tile((NT - 2) & 3); wait_vm<0>(); pipe_barrier();
  compute_tile((NT - 1) & 3); pipe_barrier();

  // ---- epilogue ----
  const int col = lane & 15;
  const int rb = (lane >> 4) * 4;
  if constexpr (MODE == 0) {
#pragma unroll
    for (int fi = 0; fi < 8; ++fi)
#pragma unroll
      for (int fj = 0; fj < 4; ++fj)
#pragma unroll
        for (int r = 0; r < 4; ++r) {
          size_t gr = bm + wm * 128 + fi * 16 + rb + r;   // row in (B*N)
          size_t gc = bn + wn * 64 + fj * 16 + col;       // out channel
          Cout[gr * 2048 + gc] = acc[fi][fj][r];
        }
  } else {
    // (1) quantize to fp16, stash in wave-private 16KB LDS (XOR-swizzled),
    //     and accumulate chunk partials of q^2
    char* W = lds + wid * 16384;
#pragma unroll
    for (int fj = 0; fj < 4; ++fj) {
      float ss = 0.f;
#pragma unroll
      for (int fi = 0; fi < 8; ++fi)
#pragma unroll
        for (int r = 0; r < 4; ++r) {
          int row_l = fi * 16 + rb + r;           // 0..127
          int d_l = fj * 16 + col;                // 0..63
          f16 q = (f16)acc[fi][fj][r];
          *(f16*)(W + row_l * 128 +
                  ((d_l * 2) ^ (((row_l >> 2) & 3) << 5))) = q;
          float qf = (float)q;
          ss += qf * qf;
        }
      ss += __shfl_xor(ss, 16);
      ss += __shfl_xor(ss, 32);
      if (lane < 16) {
        int b = (int)(bm >> 11);
        int h = (int)(bn >> 7) + (wn >> 1);
        int chunk = (int)((bm & 2047) >> 7) + wm;
        int d = (wn & 1) * 64 + fj * 16 + lane;
        psum[(((size_t)(b * 16 + h)) * 16 + chunk) * 128 + d] = ss;
      }
    }
    asm volatile("s_waitcnt lgkmcnt(0)" ::: "memory");
    __builtin_amdgcn_sched_barrier(0);
    // (2) read back f16x8 per lane -> 128B-contiguous global stores.
    // Address XOR compensates the stored involution, so the 16B block read at
    // physical (c_p*16)^(g2<<5) IS logical block c_p*16 (d = c_p*8..+7).
#pragma unroll
    for (int it = 0; it < 16; ++it) {
      int row_l = it * 8 + (lane >> 3);
      int g2 = (row_l >> 2) & 3;
      int c_p = lane & 7;
      f16x8 v = *(const f16x8*)(W + row_l * 128 + ((c_p * 16) ^ (g2 << 5)));
      size_t gr = bm + wm * 128 + row_l;
      int h = (int)(bn >> 7) + (wn >> 1);
      int d = (wn & 1) * 64 + c_p * 8;
      *(f16x8*)(Wout + (((gr >> 11) * 16 + h) * 2048 + (gr & 2047)) * 128 + d) =
          v;
    }
  }
}

// exclusive prefix over the 16 chunks, per (bh,d). 16384 threads.
__global__ __launch_bounds__(256) void k_prefix(float* __restrict__ psum) {
  int idx = blockIdx.x * 256 + threadIdx.x;  // bh*128 + d
  int bh = idx >> 7, d = idx & 127;
  float run = 0.f;
#pragma unroll
  for (int c = 0; c < 16; ++c) {
    size_t o = ((size_t)bh * 16 + c) * 128 + d;
    float v = psum[o];
    psum[o] = run;
    run += v;
  }
}

// XOR-swizzled LDS index (64KB tile, conflict-free both phases)
__device__ __forceinline__ int swz(int i, int j) { return i * 128 + (j ^ (i & 31)); }

// replay chunk scan: ratio = q^2/max(cum,eps); tmp[b,h,n] = (sum_d ratio + D*bias)*temp
__global__ __launch_bounds__(128) void k_tmp(const f16* __restrict__ w,
                                             const float* __restrict__ pre,
                                             const float* __restrict__ dbias,
                                             const float* __restrict__ temp,
                                             float* __restrict__ tmp) {
  __shared__ float ratio[128 * 128];
  int blk = blockIdx.x;
  int bh = blk >> 4, chunk = blk & 15;
  int h = bh & 15;
  int d = threadIdx.x;
  const f16* base =
      w + ((size_t)bh * 2048 + (size_t)chunk * 128) * 128 + d;
  float cum = pre[((size_t)bh * 16 + chunk) * 128 + d];
  for (int i = 0; i < 128; ++i) {
    float v = (float)base[(size_t)i * 128];
    float sq = v * v;
    cum += sq;
    float dn = fmaxf(cum, EPS_F16);
    ratio[swz(i, d)] = sq / dn;
  }
  __syncthreads();
  float s = 0.f;
#pragma unroll 8
  for (int j = 0; j < 128; ++j) s += ratio[swz(d, j)];
  int n = chunk * 128 + d;
  tmp[(size_t)bh * 2048 + n] = (s + 128.f * dbias[h * 2048 + n]) * temp[h];
}

// softmax over H=16 heads. 16384 threads, one per (b,n).
__global__ __launch_bounds__(256) void k_softmax(const float* __restrict__ tmp,
                                                 float* __restrict__ Pi) {
  int idx = blockIdx.x * 256 + threadIdx.x;  // b*2048 + n
  int b = idx >> 11, n = idx & 2047;
  float v[16];
  float mx = -1e30f;
#pragma unroll
  for (int h = 0; h < 16; ++h) {
    v[h] = tmp[((size_t)(b * 16 + h)) * 2048 + n];
    mx = fmaxf(mx, v[h]);
  }
  float s = 0.f;
#pragma unroll
  for (int h = 0; h < 16; ++h) {
    v[h] = expf(v[h] - mx);
    s += v[h];
  }
  float inv = 1.f / s;
#pragma unroll
  for (int h = 0; h < 16; ++h)
    Pi[((size_t)(b * 16 + h)) * 2048 + n] = v[h] * inv;
}

// pass C: chunk partials of q^2*Pi (per d) and Pi (scalar)
__global__ __launch_bounds__(128) void k_partial2(const f16* __restrict__ w,
                                                  const float* __restrict__ Pi,
                                                  float* __restrict__ psum,
                                                  float* __restrict__ pisum) {
  int blk = blockIdx.x;
  int bh = blk >> 4, chunk = blk & 15;
  int d = threadIdx.x;
  const f16* base =
      w + ((size_t)bh * 2048 + (size_t)chunk * 128) * 128 + d;
  const float* pib = Pi + (size_t)bh * 2048 + (size_t)chunk * 128;
  float s = 0.f, sp = 0.f;
#pragma unroll 4
  for (int i = 0; i < 128; ++i) {
    float p = pib[i];
    float v = (float)base[(size_t)i * 128];
    s += v * v * p;
    sp += p;
  }
  psum[(size_t)blk * 128 + d] = s;
  if (d == 0) pisum[blk] = sp;
}

__global__ __launch_bounds__(128) void k_prefix_pi(float* __restrict__ pisum) {
  int bh = threadIdx.x;  // 128 = B*H
  float run = 0.f;
#pragma unroll
  for (int c = 0; c < 16; ++c) {
    int o = bh * 16 + c;
    float v = pisum[o];
    pisum[o] = run;
    run += v;
  }
}

// replay: dots = cum(q^2*Pi)/(cum(Pi)+eps); y = -(q*Pi)/(1+dots), fp16, (B,N,C)
__global__ __launch_bounds__(128) void k_y(const f16* __restrict__ w,
                                           const float* __restrict__ Pi,
                                           const float* __restrict__ pre2,
                                           const float* __restrict__ piPre,
                                           f16* __restrict__ yout) {
  int blk = blockIdx.x;
  int bh = blk >> 4, chunk = blk & 15;
  int b = bh >> 4, h = bh & 15;
  int d = threadIdx.x;
  const f16* base =
      w + ((size_t)bh * 2048 + (size_t)chunk * 128) * 128 + d;
  const float* pib = Pi + (size_t)bh * 2048 + (size_t)chunk * 128;
  float cum = pre2[((size_t)bh * 16 + chunk) * 128 + d];
  float cpi = piPre[bh * 16 + chunk];
  for (int i = 0; i < 128; ++i) {
    float p = pib[i];
    float v = (float)base[(size_t)i * 128];
    cum += v * v * p;
    cpi += p;
    float dots = cum / (cpi + EPS_F16);
    float attn = 1.f / (1.f + dots);
    float y = -(v * p) * attn;
    int n = chunk * 128 + i;
    yout[((size_t)(b * 2048 + n)) * 2048 + h * 128 + d] = (f16)y;
  }
}

// ---------------- launcher ----------------
extern "C" void kernel_launch(void* const* d_in, const int* in_sizes, int n_in,
                              void* d_out, int out_size, void* d_ws, size_t ws_size,
                              hipStream_t stream) {
  const float* x     = (const float*)d_in[0];
  const float* Wa    = (const float*)d_in[1];
  const float* Wp    = (const float*)d_in[2];
  const float* temp  = (const float*)d_in[3];
  const float* dbias = (const float*)d_in[4];
  float* out = (float*)d_out;

  char* ws = (char*)d_ws;
  // workspace layout (bytes)
  constexpr size_t OFF_W   = 0;                        // w fp16 (B,H,N,D): 67108864
  constexpr size_t OFF_XH  = 67108864;                 // x fp16 (reused as y fp16): 67108864
  constexpr size_t OFF_WAH = OFF_XH + 67108864;        // W_attn fp16: 8388608
  constexpr size_t OFF_WPB = OFF_WAH + 8388608;        // W_proj fp16: 8388608
  constexpr size_t OFF_TMP = OFF_WPB + 8388608;        // tmp (B,H,N) fp32
  constexpr size_t OFF_PI  = OFF_TMP + 2097152;        // Pi  (B,H,N) fp32
  constexpr size_t OFF_PS  = OFF_PI + 2097152;         // chunk partials
  constexpr size_t OFF_PIS = OFF_PS + 1048576;         // Pi chunk partials

  f16*   w    = (f16*)(ws + OFF_W);
  f16*   xh   = (f16*)(ws + OFF_XH);   // later reused as y (fp16)
  f16*   Wah  = (f16*)(ws + OFF_WAH);
  f16*   Wpb  = (f16*)(ws + OFF_WPB);
  float* tmp  = (float*)(ws + OFF_TMP);
  float* Pi   = (float*)(ws + OFF_PI);
  float* psum = (float*)(ws + OFF_PS);
  float* pis  = (float*)(ws + OFF_PIS);

  // casts
  k_cast8h<<<16384, 256, 0, stream>>>(x, xh, 4194304LL);
  k_cast8h<<<2048, 256, 0, stream>>>(Wa, Wah, 524288LL);
  k_cast8h<<<2048, 256, 0, stream>>>(Wp, Wpb, 524288LL);

  // GEMM1 (fp16, 256^2, counted-vmcnt pipeline): w = fp16(x @ W_attn^T)
  gemm256<1><<<dim3(8, 64), 512, 0, stream>>>(xh, Wah, nullptr, w, psum);

  // scan A: prefix of chunk partials -> tmp
  k_prefix<<<64, 256, 0, stream>>>(psum);
  k_tmp<<<2048, 128, 0, stream>>>(w, psum, dbias, temp, tmp);

  // softmax over heads
  k_softmax<<<64, 256, 0, stream>>>(tmp, Pi);

  // scan C: cum(q^2*Pi), cum(Pi) -> y (fp16, reuses xh buffer)
  k_partial2<<<2048, 128, 0, stream>>>(w, Pi, psum, pis);
  k_prefix<<<64, 256, 0, stream>>>(psum);
  k_prefix_pi<<<1, 128, 0, stream>>>(pis);
  k_y<<<2048, 128, 0, stream>>>(w, Pi, psum, pis, xh);

  // GEMM2 (fp16, 256^2, counted-vmcnt pipeline): out = y @ W_proj^T
  gemm256<0><<<dim3(8, 64), 512, 0, stream>>>(xh, Wpb, out, nullptr, nullptr);
}